// Round 11
// baseline (293.954 us; speedup 1.0000x reference)
//
#include <hip/hip_runtime.h>

// Masked self-attention, B=4 T=2048 C=1024 (single head, head dim = C).
// Two GEMM engines:
//  gemm8 : 256x256 / BK=64 / 8-wave 4-barrier pipelined (round-8 schedule,
//          vmcnt(4)) — used for QK-proj only (1 block/CU, 860 TF class).
//  gemm4 : 128x128 / BK=64 / 4-wave / 32 KB LDS single-buffered 2-barrier
//          (m97 lineage): ~4 blocks/CU so other blocks' waves hide each
//          block's staging drain. Conflict-free 128B-row slot-XOR swizzle
//          (slot ^= row&7), both-sides. Used for Vt-proj, scores(+exp+rowsum),
//          PV (causal-clamped, /rowsum, longest-first order), out-proj.
// No softmax pass, no split-K partials, no reduce pass.
// Round-11 fix: PV epilogue applies z*sCz (round 10 clobbered batches).
// Pipeline: prep | QK(gemm8) | Vt(gemm4) | scores(gemm4) | PV(gemm4) | out(gemm4)

typedef __attribute__((ext_vector_type(8))) short short8;
typedef __attribute__((ext_vector_type(4))) float f32x4;
typedef __attribute__((ext_vector_type(4))) unsigned short us4;
typedef __attribute__((ext_vector_type(4))) float fl4;

__device__ __forceinline__ unsigned short f2b(float f) {
  unsigned int u = __builtin_bit_cast(unsigned int, f);
  u += 0x7fffu + ((u >> 16) & 1u);   // round-to-nearest-even
  return (unsigned short)(u >> 16);
}

// ---------------- merged prep: converts + bias packing + rowsum zero -------
__global__ __launch_bounds__(256) void prep_kernel(
    const float* __restrict__ x,
    const float* __restrict__ Wq, const float* __restrict__ Wk,
    const float* __restrict__ Wv, const float* __restrict__ Wo,
    const float* __restrict__ bq, const float* __restrict__ bk,
    const float* __restrict__ bv, const float* __restrict__ bo,
    unsigned short* __restrict__ xb, unsigned short* __restrict__ Wqkvb,
    unsigned short* __restrict__ Wob, float* __restrict__ bws,
    float* __restrict__ rows) {
  const int bid = blockIdx.x;
  if (bid < 8192) {
    const int i = bid * 256 + threadIdx.x;
    fl4 f = *(const fl4*)&x[(size_t)i << 2];
    us4 o;
#pragma unroll
    for (int j = 0; j < 4; ++j) o[j] = f2b(f[j]);
    *(us4*)&xb[(size_t)i << 2] = o;
  } else if (bid < 12288) {
    const int w = (bid - 8192) >> 10;
    const int i = ((bid - 8192) & 1023) * 256 + threadIdx.x;
    const float* s = w == 0 ? Wq : w == 1 ? Wk : w == 2 ? Wv : Wo;
    unsigned short* d = w < 3 ? Wqkvb + (size_t)w * 1024 * 1024 : Wob;
    fl4 f = *(const fl4*)&s[(size_t)i << 2];
    us4 o;
#pragma unroll
    for (int j = 0; j < 4; ++j) o[j] = f2b(f[j]);
    *(us4*)&d[(size_t)i << 2] = o;
  } else if (bid < 12304) {
    const int i = (bid - 12288) * 256 + threadIdx.x;
    const int sel = i >> 10, idx = i & 1023;
    const float* p = sel == 0 ? bq : sel == 1 ? bk : sel == 2 ? bv : bo;
    bws[i] = p[idx];
  } else {
    for (int k = threadIdx.x; k < 8192; k += 256) rows[k] = 0.f;
  }
}

#define RD_A(dst, basep)                                                   \
  _Pragma("unroll") for (int mi = 0; mi < 4; ++mi)                         \
  _Pragma("unroll") for (int ks = 0; ks < 2; ++ks)                         \
      dst[mi][ks] = *(const short8*)((basep) + offA[mi][ks]);

#define RD_B(dst, basep)                                                   \
  _Pragma("unroll") for (int nj = 0; nj < 2; ++nj)                         \
  _Pragma("unroll") for (int ks = 0; ks < 2; ++ks)                         \
      dst[nj][ks] = *(const short8*)((basep) + offB[nj][ks]);

#define MFMA16(AF, BF, MI0, NJ0)                                           \
  __builtin_amdgcn_s_setprio(1);                                           \
  _Pragma("unroll") for (int ks = 0; ks < 2; ++ks)                         \
  _Pragma("unroll") for (int mi = 0; mi < 4; ++mi)                         \
  _Pragma("unroll") for (int nj = 0; nj < 2; ++nj)                         \
      acc[(MI0) + mi][(NJ0) + nj] = __builtin_amdgcn_mfma_f32_16x16x32_bf16( \
          AF[mi][ks], BF[nj][ks], acc[(MI0) + mi][(NJ0) + nj], 0, 0, 0);   \
  __builtin_amdgcn_s_setprio(0);

// ---------------- gemm8: 256x256 4-barrier pipelined (round-8 exact) -------
// bf16 + bias[col].  Used for QK projection.
__global__ __launch_bounds__(512, 2)
void gemm8(const unsigned short* __restrict__ A, const unsigned short* __restrict__ B,
           unsigned short* __restrict__ Cout, const float* __restrict__ bias,
           int K, int lda, int ldb, int ldc)
{
  const int gx = gridDim.x;
  const int nwg = gx * gridDim.y;
  int flat = blockIdx.y * gx + blockIdx.x;
  { const int q = nwg >> 3, r = nwg & 7, xc = flat & 7, i = flat >> 3;
    flat = (xc < r ? xc * (q + 1) : r * (q + 1) + (xc - r) * q) + i; }
  const int m0 = (flat / gx) << 8;
  const int n0 = (flat % gx) << 8;
  const int nt = K >> 6;

  __shared__ unsigned short lA[2][2][8192];
  __shared__ unsigned short lB[2][2][8192];

  const int tid = threadIdx.x, lane = tid & 63, wid = tid >> 6;
  const int wm = wid >> 2, wn = wid & 3;
  const int fr = lane & 15, kg = lane >> 4;

  const int xorv = (fr & 7) << 4;
  int offA[4][2], offB[2][2];
#pragma unroll
  for (int mi = 0; mi < 4; ++mi)
#pragma unroll
    for (int ks = 0; ks < 2; ++ks)
      offA[mi][ks] = ((wm << 6) + (mi << 4) + fr) * 128 + (((ks << 6) + (kg << 4)) ^ xorv);
#pragma unroll
  for (int nj = 0; nj < 2; ++nj)
#pragma unroll
    for (int ks = 0; ks < 2; ++ks)
      offB[nj][ks] = ((wn << 5) + (nj << 4) + fr) * 128 + (((ks << 6) + (kg << 4)) ^ xorv);

  const int srow = tid >> 3;
  const int scol = (((tid & 7) ^ (srow & 7)) << 3);
  const unsigned short* aS = A + (size_t)(m0 + srow) * lda + scol;
  const unsigned short* bS = B + (size_t)(n0 + srow) * ldb + scol;

  auto stA = [&](int buf, int h, int tt) {
    int ttc = tt < nt ? tt : nt - 1;
    const unsigned short* s0 = aS + (size_t)(h << 7) * lda + (ttc << 6);
#pragma unroll
    for (int c = 0; c < 2; ++c)
      __builtin_amdgcn_global_load_lds(
          (const __attribute__((address_space(1))) void*)(s0 + (size_t)(c << 6) * lda),
          (__attribute__((address_space(3))) void*)((char*)&lA[buf][h][0] + (c << 13) + (tid << 4)),
          16, 0, 0);
  };
  auto stB = [&](int buf, int h, int tt) {
    int ttc = tt < nt ? tt : nt - 1;
    const unsigned short* s0 = bS + (size_t)(h << 7) * ldb + (ttc << 6);
#pragma unroll
    for (int c = 0; c < 2; ++c)
      __builtin_amdgcn_global_load_lds(
          (const __attribute__((address_space(1))) void*)(s0 + (size_t)(c << 6) * ldb),
          (__attribute__((address_space(3))) void*)((char*)&lB[buf][h][0] + (c << 13) + (tid << 4)),
          16, 0, 0);
  };

  f32x4 acc[8][4];
#pragma unroll
  for (int i = 0; i < 8; ++i)
#pragma unroll
    for (int j = 0; j < 4; ++j) acc[i][j] = f32x4{0.f, 0.f, 0.f, 0.f};

  stA(0, 0, 0); stB(0, 0, 0); stA(0, 1, 0); stB(0, 1, 0); stB(1, 0, 1); stA(1, 1, 1);
  asm volatile("s_waitcnt vmcnt(4)" ::: "memory");
  __builtin_amdgcn_s_barrier();

  for (int t = 0; t < nt; ++t) {
    const int buf = t & 1, nbuf = buf ^ 1;
    const char* Ab0 = (const char*)&lA[buf][0][0];
    const char* Ab1 = (const char*)&lA[buf][1][0];
    const char* Bb0 = (const char*)&lB[buf][0][0];
    const char* Bb1 = (const char*)&lB[buf][1][0];

    short8 a0[4][2], a1[4][2], b0[2][2], b1[2][2];

    RD_A(a0, Ab0);
    RD_B(b0, Bb0);
    stB(nbuf, 1, t + 1);
    __builtin_amdgcn_s_barrier();
    RD_A(a1, Ab1);
    MFMA16(a0, b0, 0, 0);

    stA(nbuf, 0, t + 1);
    __builtin_amdgcn_s_barrier();
    RD_B(b1, Bb1);
    MFMA16(a1, b0, 4, 0);

    stB(buf, 0, t + 2);
    __builtin_amdgcn_s_barrier();
    MFMA16(a1, b1, 4, 2);

    stA(buf, 1, t + 2);
    asm volatile("s_waitcnt vmcnt(4)" ::: "memory");
    __builtin_amdgcn_s_barrier();
    MFMA16(a0, b1, 0, 2);
  }
  asm volatile("s_waitcnt vmcnt(0)" ::: "memory");

#pragma unroll
  for (int mig = 0; mig < 8; ++mig)
#pragma unroll
    for (int njg = 0; njg < 4; ++njg) {
      const int row = m0 + (mig >> 2) * 128 + wm * 64 + (mig & 3) * 16 + (kg << 2);
      const int col = n0 + (njg >> 1) * 128 + wn * 32 + (njg & 1) * 16 + fr;
      f32x4 v = acc[mig][njg];
      const float bb = bias[col];
#pragma unroll
      for (int jj = 0; jj < 4; ++jj)
        Cout[(size_t)(row + jj) * ldc + col] = f2b(v[jj] + bb);
    }
}

// ---------------- gemm4: 128x128 / BK=64 / 4-wave / single-buffered --------
// EPI: 0 = Vt-proj (bf16 + bias[row])     1 = scores (exp*mask + rowsum)
//      2 = PV (bf16 * 1/rowsum[row], + z*sCz)   3 = out-proj (f32 + bias[col])
template<int EPI>
__global__ __launch_bounds__(256, 4)
void gemm4(const unsigned short* __restrict__ A, const unsigned short* __restrict__ B,
           void* __restrict__ Cout, const float* __restrict__ bias,
           float* __restrict__ rows, float scale, int K,
           int lda, int ldb, int ldc,
           long long sAz, long long sBz, long long sCz)
{
  int m0, n0, z = 0, kEnd = K;
  if (EPI == 1) {
    // scores: 1-D tri grid (544 = 4 batches x 136), XCD-chunked (544%8==0)
    int id = blockIdx.x;
    id = (id & 7) * (gridDim.x >> 3) + (id >> 3);
    z = id / 136;
    int t = id % 136, i = 0;
    while ((i + 1) * (i + 2) / 2 <= t) ++i;
    m0 = i << 7;
    n0 = (t - i * (i + 1) / 2) << 7;
  } else if (EPI == 2) {
    // PV: 1-D, longest-first (my descending); 512 = 16 my x (4 z x 8 nx)
    const int id = blockIdx.x;
    const int my = 15 - (id >> 5);
    z = (id & 31) >> 3;
    m0 = my << 7;
    n0 = (id & 7) << 7;
    kEnd = m0 + 128;                     // causal clamp
  } else {
    const int gx = gridDim.x;
    const int nwg = gx * gridDim.y;
    int flat = blockIdx.y * gx + blockIdx.x;
    { const int q = nwg >> 3, r = nwg & 7, xc = flat & 7, i = flat >> 3;
      flat = (xc < r ? xc * (q + 1) : r * (q + 1) + (xc - r) * q) + i; }
    m0 = (flat / gx) << 7;
    n0 = (flat % gx) << 7;
  }
  const int nt = kEnd >> 6;

  __shared__ unsigned short lA[128 * 64];   // 16 KB
  __shared__ unsigned short lB[128 * 64];   // 16 KB

  const int tid = threadIdx.x, lane = tid & 63, wid = tid >> 6;
  const int wm = wid >> 1, wn = wid & 1;    // 2 x 2 waves, 64x64 each
  const int fr = lane & 15, kg = lane >> 4;

  const unsigned short* Ab = A + (size_t)z * sAz;
  const unsigned short* Bb = B + (size_t)z * sBz;

  // ds_read byte offsets: 128B rows, 16B-slot ^= (row&7)
  const int xorv = (fr & 7) << 4;
  int offA[4][2], offB[4][2];
#pragma unroll
  for (int mi = 0; mi < 4; ++mi)
#pragma unroll
    for (int ks = 0; ks < 2; ++ks) {
      offA[mi][ks] = ((wm << 6) + (mi << 4) + fr) * 128 + (((ks << 6) + (kg << 4)) ^ xorv);
      offB[mi][ks] = ((wn << 6) + (mi << 4) + fr) * 128 + (((ks << 6) + (kg << 4)) ^ xorv);
    }

  // staging: 256 thr x 16B = 4 KB = 32 rows per call; 4 calls each operand
  const int srow = tid >> 3;                 // 0..31 (+32c)
  const int scol = (((tid & 7) ^ (srow & 7)) << 3);
  const unsigned short* aS = Ab + (size_t)(m0 + srow) * lda + scol;
  const unsigned short* bS = Bb + (size_t)(n0 + srow) * ldb + scol;

  f32x4 acc[4][4];
#pragma unroll
  for (int i = 0; i < 4; ++i)
#pragma unroll
    for (int j = 0; j < 4; ++j) acc[i][j] = f32x4{0.f, 0.f, 0.f, 0.f};

  for (int t = 0; t < nt; ++t) {
    __syncthreads();                         // prev tile's reads done
    const int k0 = t << 6;
#pragma unroll
    for (int c = 0; c < 4; ++c) {
      __builtin_amdgcn_global_load_lds(
          (const __attribute__((address_space(1))) void*)(aS + (size_t)(c << 5) * lda + k0),
          (__attribute__((address_space(3))) void*)((char*)lA + (c << 12) + (tid << 4)),
          16, 0, 0);
      __builtin_amdgcn_global_load_lds(
          (const __attribute__((address_space(1))) void*)(bS + (size_t)(c << 5) * ldb + k0),
          (__attribute__((address_space(3))) void*)((char*)lB + (c << 12) + (tid << 4)),
          16, 0, 0);
    }
    __syncthreads();                         // compiler drains vmcnt(0)

    short8 af[4][2], bf[4][2];
#pragma unroll
    for (int mi = 0; mi < 4; ++mi)
#pragma unroll
      for (int ks = 0; ks < 2; ++ks) {
        af[mi][ks] = *(const short8*)((const char*)lA + offA[mi][ks]);
        bf[mi][ks] = *(const short8*)((const char*)lB + offB[mi][ks]);
      }
    __builtin_amdgcn_s_setprio(1);
#pragma unroll
    for (int ks = 0; ks < 2; ++ks)
#pragma unroll
      for (int mi = 0; mi < 4; ++mi)
#pragma unroll
        for (int nj = 0; nj < 4; ++nj)
          acc[mi][nj] = __builtin_amdgcn_mfma_f32_16x16x32_bf16(
              af[mi][ks], bf[nj][ks], acc[mi][nj], 0, 0, 0);
    __builtin_amdgcn_s_setprio(0);
  }

  // epilogue: C frag col=lane&15, row=(lane>>4)*4+reg
  if (EPI == 1) {
    unsigned short* Ch = (unsigned short*)Cout + (size_t)z * sCz;
#pragma unroll
    for (int mi = 0; mi < 4; ++mi) {
      const int row = m0 + wm * 64 + mi * 16 + (kg << 2);
#pragma unroll
      for (int jj = 0; jj < 4; ++jj) {
        const int r = row + jj;
        float rs = 0.f;
#pragma unroll
        for (int nj = 0; nj < 4; ++nj) {
          const int col = n0 + wn * 64 + nj * 16 + fr;
          const float ee = (col <= r) ? __expf(acc[mi][nj][jj] * scale) : 0.f;
          rs += ee;
          Ch[(size_t)r * ldc + col] = f2b(ee);
        }
#pragma unroll
        for (int mk = 1; mk <= 8; mk <<= 1) rs += __shfl_xor(rs, mk, 64);
        if (fr == 0) atomicAdd(&rows[z * 2048 + r], rs);
      }
    }
    return;
  }
#pragma unroll
  for (int mi = 0; mi < 4; ++mi)
#pragma unroll
    for (int nj = 0; nj < 4; ++nj) {
      const int row = m0 + wm * 64 + mi * 16 + (kg << 2);
      const int col = n0 + wn * 64 + nj * 16 + fr;
      f32x4 v = acc[mi][nj];
      if (EPI == 0) {          // Vt-proj: bf16 + bias[row]
        unsigned short* Ch = (unsigned short*)Cout;
#pragma unroll
        for (int jj = 0; jj < 4; ++jj)
          Ch[(size_t)(row + jj) * ldc + col] = f2b(v[jj] + bias[row + jj]);
      } else if (EPI == 2) {   // PV: bf16 * 1/rowsum[row], batch offset z*sCz
        unsigned short* Ch = (unsigned short*)Cout + (size_t)z * sCz;
#pragma unroll
        for (int jj = 0; jj < 4; ++jj) {
          const float inv = 1.f / rows[z * 2048 + row + jj];
          Ch[(size_t)(row + jj) * ldc + col] = f2b(v[jj] * inv);
        }
      } else {                 // out-proj: f32 + bias[col]
        float* Cf = (float*)Cout;
        const float bb = bias[col];
#pragma unroll
        for (int jj = 0; jj < 4; ++jj)
          Cf[(size_t)(row + jj) * ldc + col] = v[jj] + bb;
      }
    }
}

// ---------------- host-side launch ----------------
extern "C" void kernel_launch(void* const* d_in, const int* in_sizes, int n_in,
                              void* d_out, int out_size, void* d_ws, size_t ws_size,
                              hipStream_t stream) {
  (void)in_sizes; (void)n_in; (void)out_size; (void)ws_size;
  const float* x  = (const float*)d_in[0];
  const float* Wq = (const float*)d_in[1];
  const float* bq = (const float*)d_in[2];
  const float* Wk = (const float*)d_in[3];
  const float* bk = (const float*)d_in[4];
  const float* Wv = (const float*)d_in[5];
  const float* bv = (const float*)d_in[6];
  const float* Wo = (const float*)d_in[7];
  const float* bo = (const float*)d_in[8];

  const int B = 4, T = 2048, C = 1024;
  const int M = B * T;                                   // 8192

  unsigned short* xb    = (unsigned short*)d_ws;         // M*C ; later attn
  unsigned short* Wqkvb = xb    + (size_t)M * C;         // [Wq|Wk|Wv]
  unsigned short* Wob   = Wqkvb + (size_t)3 * C * C;
  unsigned short* QK    = Wob   + (size_t)C * C;         // M*2C [Q|K]
  unsigned short* Vt    = QK    + (size_t)M * 2 * C;     // [1024][8192]
  unsigned short* S     = Vt    + (size_t)M * C;         // B*T*T e-values
  float*          bws   = (float*)(S + (size_t)B * T * T);
  float*          rowsum= bws + 4096;                    // 8192 f32
  unsigned short* attn  = xb;                            // xb dead after Vt-proj

  // 1. prep: converts + packing + rowsum zero
  prep_kernel<<<12305, 256, 0, stream>>>(x, Wq, Wk, Wv, Wo, bq, bk, bv, bo,
                                         xb, Wqkvb, Wob, bws, rowsum);

  // 2. QK projection: QK[t][0:2048] = x @ [Wq|Wk]^T + [bq|bk]  (gemm8)
  gemm8<<<dim3(2 * C / 256, M / 256, 1), 512, 0, stream>>>(
      xb, Wqkvb, QK, bws, C, C, C, 2 * C);

  // 3. Vt = Wv @ x^T + bv[row]: Vt[c][t_glob]  (gemm4, 512 blocks)
  gemm4<0><<<dim3(M / 128, C / 128, 1), 256, 0, stream>>>(
      Wqkvb + (size_t)2 * C * C, xb, Vt, bws + 2 * C, nullptr, 1.f,
      C, C, C, M, 0LL, 0LL, 0LL);

  // 4. scores: S = exp(Q K^T / 32) causal-masked + rowsum (gemm4, 544 tri)
  gemm4<1><<<544, 256, 0, stream>>>(
      QK, QK + C, S, nullptr, rowsum, 0.03125f,
      C, 2 * C, 2 * C, T,
      (long long)T * 2 * C, (long long)T * 2 * C, (long long)T * T);

  // 5. PV: attn = (S @ V) / rowsum  (gemm4, 512 blocks, longest-first)
  gemm4<2><<<512, 256, 0, stream>>>(
      S, Vt, attn, nullptr, rowsum, 1.f,
      T, T, M, C,
      (long long)T * T, 2048LL, (long long)T * C);

  // 6. out = attn Wo^T + bo (f32)  (gemm4, 512 blocks)
  gemm4<3><<<dim3(C / 128, M / 128, 1), 256, 0, stream>>>(
      attn, Wob, d_out, bws + 3 * C, nullptr, 1.f,
      C, C, C, C, 0LL, 0LL, 0LL);
}

// Round 12
// 193.303 us; speedup vs baseline: 1.5207x; 1.5207x over previous
//
#include <hip/hip_runtime.h>

// Masked self-attention, B=4 T=2048 C=1024 (single head, head dim = C).
// Round-8 configuration (best measured: 188 µs) + one change: scores and
// Vt-proj (independent GEMMs) merged into ONE 272-block launch (fused_sv)
// to fill the machine (scores alone uses 144/256 CUs).
//  gemm8   : 256x256 / BK=64 / 8-wave 4-barrier pipelined loop, vmcnt(4).
//  fused_sv: same loop; blocks 0-143 = tri-packed scores (exp+rowsum),
//            blocks 144-271 = Vt = Wv @ x^T + bv[row].
//  gemm2ph : 256x128 2-phase (out-proj, full-machine 256-block grid).
// PV split-K=4 partials (P0..P3) -> reduce_pv4 (/rowsum).
// Pipeline: prep | QK(gemm8) | fused_sv | PV(gemm8 splitK4) | reduce | out.

typedef __attribute__((ext_vector_type(8))) short short8;
typedef __attribute__((ext_vector_type(4))) float f32x4;
typedef __attribute__((ext_vector_type(4))) unsigned short us4;
typedef __attribute__((ext_vector_type(8))) unsigned short us8;
typedef __attribute__((ext_vector_type(4))) float fl4;

__device__ __forceinline__ unsigned short f2b(float f) {
  unsigned int u = __builtin_bit_cast(unsigned int, f);
  u += 0x7fffu + ((u >> 16) & 1u);   // round-to-nearest-even
  return (unsigned short)(u >> 16);
}
__device__ __forceinline__ float b2f(unsigned short h) {
  unsigned int u = ((unsigned int)h) << 16;
  return __builtin_bit_cast(float, u);
}

// ---------------- merged prep: converts + bias packing + rowsum zero -------
__global__ __launch_bounds__(256) void prep_kernel(
    const float* __restrict__ x,
    const float* __restrict__ Wq, const float* __restrict__ Wk,
    const float* __restrict__ Wv, const float* __restrict__ Wo,
    const float* __restrict__ bq, const float* __restrict__ bk,
    const float* __restrict__ bv, const float* __restrict__ bo,
    unsigned short* __restrict__ xb, unsigned short* __restrict__ Wqkvb,
    unsigned short* __restrict__ Wob, float* __restrict__ bws,
    float* __restrict__ rows) {
  const int bid = blockIdx.x;
  if (bid < 8192) {
    const int i = bid * 256 + threadIdx.x;
    fl4 f = *(const fl4*)&x[(size_t)i << 2];
    us4 o;
#pragma unroll
    for (int j = 0; j < 4; ++j) o[j] = f2b(f[j]);
    *(us4*)&xb[(size_t)i << 2] = o;
  } else if (bid < 12288) {
    const int w = (bid - 8192) >> 10;
    const int i = ((bid - 8192) & 1023) * 256 + threadIdx.x;
    const float* s = w == 0 ? Wq : w == 1 ? Wk : w == 2 ? Wv : Wo;
    unsigned short* d = w < 3 ? Wqkvb + (size_t)w * 1024 * 1024 : Wob;
    fl4 f = *(const fl4*)&s[(size_t)i << 2];
    us4 o;
#pragma unroll
    for (int j = 0; j < 4; ++j) o[j] = f2b(f[j]);
    *(us4*)&d[(size_t)i << 2] = o;
  } else if (bid < 12304) {
    const int i = (bid - 12288) * 256 + threadIdx.x;
    const int sel = i >> 10, idx = i & 1023;
    const float* p = sel == 0 ? bq : sel == 1 ? bk : sel == 2 ? bv : bo;
    bws[i] = p[idx];
  } else {
    for (int k = threadIdx.x; k < 8192; k += 256) rows[k] = 0.f;
  }
}

#define RD_A(dst, basep)                                                   \
  _Pragma("unroll") for (int mi = 0; mi < 4; ++mi)                         \
  _Pragma("unroll") for (int ks = 0; ks < 2; ++ks)                         \
      dst[mi][ks] = *(const short8*)((basep) + offA[mi][ks]);

#define RD_B(dst, basep)                                                   \
  _Pragma("unroll") for (int nj = 0; nj < 2; ++nj)                         \
  _Pragma("unroll") for (int ks = 0; ks < 2; ++ks)                         \
      dst[nj][ks] = *(const short8*)((basep) + offB[nj][ks]);

#define MFMA16(AF, BF, MI0, NJ0)                                           \
  __builtin_amdgcn_s_setprio(1);                                           \
  _Pragma("unroll") for (int ks = 0; ks < 2; ++ks)                         \
  _Pragma("unroll") for (int mi = 0; mi < 4; ++mi)                         \
  _Pragma("unroll") for (int nj = 0; nj < 2; ++nj)                         \
      acc[(MI0) + mi][(NJ0) + nj] = __builtin_amdgcn_mfma_f32_16x16x32_bf16( \
          AF[mi][ks], BF[nj][ks], acc[(MI0) + mi][(NJ0) + nj], 0, 0, 0);   \
  __builtin_amdgcn_s_setprio(0);

// Shared 4-barrier pipelined K-loop body (round-8 schedule), as a macro over
// locals: lA,lB,nt,offA,offB,stA,stB,acc.
#define KLOOP_BODY                                                         \
  stA(0, 0, 0); stB(0, 0, 0); stA(0, 1, 0); stB(0, 1, 0);                  \
  stB(1, 0, 1); stA(1, 1, 1);                                              \
  asm volatile("s_waitcnt vmcnt(4)" ::: "memory");                         \
  __builtin_amdgcn_s_barrier();                                            \
  for (int t = 0; t < nt; ++t) {                                           \
    const int buf = t & 1, nbuf = buf ^ 1;                                 \
    const char* Ab0 = (const char*)&lA[buf][0][0];                         \
    const char* Ab1 = (const char*)&lA[buf][1][0];                         \
    const char* Bb0 = (const char*)&lB[buf][0][0];                         \
    const char* Bb1 = (const char*)&lB[buf][1][0];                         \
    short8 a0[4][2], a1[4][2], b0[2][2], b1[2][2];                         \
    RD_A(a0, Ab0);                                                         \
    RD_B(b0, Bb0);                                                         \
    stB(nbuf, 1, t + 1);                                                   \
    __builtin_amdgcn_s_barrier();                                          \
    RD_A(a1, Ab1);                                                         \
    MFMA16(a0, b0, 0, 0);                                                  \
    stA(nbuf, 0, t + 1);                                                   \
    __builtin_amdgcn_s_barrier();                                          \
    RD_B(b1, Bb1);                                                         \
    MFMA16(a1, b0, 4, 0);                                                  \
    stB(buf, 0, t + 2);                                                    \
    __builtin_amdgcn_s_barrier();                                          \
    MFMA16(a1, b1, 4, 2);                                                  \
    stA(buf, 1, t + 2);                                                    \
    asm volatile("s_waitcnt vmcnt(4)" ::: "memory");                       \
    __builtin_amdgcn_s_barrier();                                          \
    MFMA16(a0, b1, 0, 2);                                                  \
  }                                                                        \
  asm volatile("s_waitcnt vmcnt(0)" ::: "memory");

// ---------------- gemm8: 256x256 4-barrier pipelined (round-8 exact) -------
// EPI: 3 = bf16 + bias[col]   5 = split-K4 bf16 partial (quarter -> 4 bufs)
template<int EPI, bool SPLIT4>
__global__ __launch_bounds__(512, 2)
void gemm8(const unsigned short* __restrict__ A, const unsigned short* __restrict__ B,
           void* __restrict__ Cout, const float* __restrict__ bias,
           float* __restrict__ rows, int K,
           int lda, int ldb, int ldc,
           long long sAz, long long sBz, long long sCz)
{
  const int gx = gridDim.x;
  const int nwg = gx * gridDim.y;
  int flat = blockIdx.y * gx + blockIdx.x;
  { const int q = nwg >> 3, r = nwg & 7, xc = flat & 7, i = flat >> 3;
    flat = (xc < r ? xc * (q + 1) : r * (q + 1) + (xc - r) * q) + i; }
  const int m0 = (flat / gx) << 8;
  const int n0 = (flat % gx) << 8;
  const int zraw = blockIdx.z;
  const int z = SPLIT4 ? (zraw >> 2) : zraw;

  int kBeg = 0, kEnd = K;
  if (SPLIT4) {
    const int quarter = (m0 + 256) >> 2;       // multiple of 64
    kBeg = (zraw & 3) * quarter;
    kEnd = kBeg + quarter;
  }
  const int nt = (kEnd - kBeg) >> 6;

  __shared__ unsigned short lA[2][2][8192];
  __shared__ unsigned short lB[2][2][8192];

  const int tid = threadIdx.x, lane = tid & 63, wid = tid >> 6;
  const int wm = wid >> 2, wn = wid & 3;
  const int fr = lane & 15, kg = lane >> 4;

  const unsigned short* Ab = A + (size_t)z * sAz;
  const unsigned short* Bb = B + (size_t)z * sBz;

  const int xorv = (fr & 7) << 4;
  int offA[4][2], offB[2][2];
#pragma unroll
  for (int mi = 0; mi < 4; ++mi)
#pragma unroll
    for (int ks = 0; ks < 2; ++ks)
      offA[mi][ks] = ((wm << 6) + (mi << 4) + fr) * 128 + (((ks << 6) + (kg << 4)) ^ xorv);
#pragma unroll
  for (int nj = 0; nj < 2; ++nj)
#pragma unroll
    for (int ks = 0; ks < 2; ++ks)
      offB[nj][ks] = ((wn << 5) + (nj << 4) + fr) * 128 + (((ks << 6) + (kg << 4)) ^ xorv);

  const int srow = tid >> 3;
  const int scol = (((tid & 7) ^ (srow & 7)) << 3);
  const unsigned short* aS = Ab + (size_t)(m0 + srow) * lda + scol + kBeg;
  const unsigned short* bS = Bb + (size_t)(n0 + srow) * ldb + scol + kBeg;

  auto stA = [&](int buf, int h, int tt) {
    int ttc = tt < nt ? tt : nt - 1;
    const unsigned short* s0 = aS + (size_t)(h << 7) * lda + (ttc << 6);
#pragma unroll
    for (int c = 0; c < 2; ++c)
      __builtin_amdgcn_global_load_lds(
          (const __attribute__((address_space(1))) void*)(s0 + (size_t)(c << 6) * lda),
          (__attribute__((address_space(3))) void*)((char*)&lA[buf][h][0] + (c << 13) + (tid << 4)),
          16, 0, 0);
  };
  auto stB = [&](int buf, int h, int tt) {
    int ttc = tt < nt ? tt : nt - 1;
    const unsigned short* s0 = bS + (size_t)(h << 7) * ldb + (ttc << 6);
#pragma unroll
    for (int c = 0; c < 2; ++c)
      __builtin_amdgcn_global_load_lds(
          (const __attribute__((address_space(1))) void*)(s0 + (size_t)(c << 6) * ldb),
          (__attribute__((address_space(3))) void*)((char*)&lB[buf][h][0] + (c << 13) + (tid << 4)),
          16, 0, 0);
  };

  f32x4 acc[8][4];
#pragma unroll
  for (int i = 0; i < 8; ++i)
#pragma unroll
    for (int j = 0; j < 4; ++j) acc[i][j] = f32x4{0.f, 0.f, 0.f, 0.f};

  KLOOP_BODY

#pragma unroll
  for (int mig = 0; mig < 8; ++mig)
#pragma unroll
    for (int njg = 0; njg < 4; ++njg) {
      const int row = m0 + (mig >> 2) * 128 + wm * 64 + (mig & 3) * 16 + (kg << 2);
      const int col = n0 + (njg >> 1) * 128 + wn * 32 + (njg & 1) * 16 + fr;
      f32x4 v = acc[mig][njg];
      if (EPI == 3) {
        unsigned short* Ch = (unsigned short*)Cout;
        const float bb = bias[col];
#pragma unroll
        for (int jj = 0; jj < 4; ++jj)
          Ch[(size_t)(row + jj) * ldc + col] = f2b(v[jj] + bb);
      } else {   // EPI == 5: split-K4 partial; quarter selects buffer
        const int q = zraw & 3;
        unsigned short* Ch =
            (q == 0) ? (unsigned short*)Cout :
            (q == 1) ? (unsigned short*)Cout + 8388608 :
            (q == 2) ? (unsigned short*)bias :       // P2 buffer (cast)
                       (unsigned short*)rows;        // P3 buffer (cast)
        Ch += (size_t)z * sCz;
#pragma unroll
        for (int jj = 0; jj < 4; ++jj)
          Ch[(size_t)(row + jj) * ldc + col] = f2b(v[jj]);
      }
    }
}

// ------- fused_sv: scores (tri, exp+rowsum) + Vt-proj in ONE launch --------
// 272 blocks = 144 scores (4 batches x 36 tri) + 128 Vt (4 m x 32 n).
__global__ __launch_bounds__(512, 2)
void fused_sv(const unsigned short* __restrict__ QK,
              const unsigned short* __restrict__ xb,
              const unsigned short* __restrict__ Wvb,
              unsigned short* __restrict__ S,
              unsigned short* __restrict__ Vt,
              float* __restrict__ rows, const float* __restrict__ bv)
{
  int id = blockIdx.x;                 // 272 = 8 * 34 (XCD-chunked)
  id = (id & 7) * 34 + (id >> 3);

  const unsigned short* A;
  const unsigned short* B;
  int m0, n0, lda, ldb, z = 0;
  bool isScore;
  if (id < 144) {
    isScore = true;
    z = id / 36;
    int t = id % 36, i = 0;
    while ((i + 1) * (i + 2) / 2 <= t) ++i;
    m0 = i << 8;
    n0 = (t - i * (i + 1) / 2) << 8;
    A = QK + (size_t)z * 2048 * 2048;          // Q half (cols 0..1023)
    B = QK + (size_t)z * 2048 * 2048 + 1024;   // K half
    lda = 2048; ldb = 2048;
  } else {
    isScore = false;
    const int v = id - 144;
    m0 = (v & 3) << 8;                          // Wv rows (1024)
    n0 = (v >> 2) << 8;                         // x rows (8192)
    A = Wvb; B = xb;
    lda = 1024; ldb = 1024;
  }
  const int nt = 16;                            // K = 1024 both roles

  __shared__ unsigned short lA[2][2][8192];
  __shared__ unsigned short lB[2][2][8192];

  const int tid = threadIdx.x, lane = tid & 63, wid = tid >> 6;
  const int wm = wid >> 2, wn = wid & 3;
  const int fr = lane & 15, kg = lane >> 4;

  const int xorv = (fr & 7) << 4;
  int offA[4][2], offB[2][2];
#pragma unroll
  for (int mi = 0; mi < 4; ++mi)
#pragma unroll
    for (int ks = 0; ks < 2; ++ks)
      offA[mi][ks] = ((wm << 6) + (mi << 4) + fr) * 128 + (((ks << 6) + (kg << 4)) ^ xorv);
#pragma unroll
  for (int nj = 0; nj < 2; ++nj)
#pragma unroll
    for (int ks = 0; ks < 2; ++ks)
      offB[nj][ks] = ((wn << 5) + (nj << 4) + fr) * 128 + (((ks << 6) + (kg << 4)) ^ xorv);

  const int srow = tid >> 3;
  const int scol = (((tid & 7) ^ (srow & 7)) << 3);
  const unsigned short* aS = A + (size_t)(m0 + srow) * lda + scol;
  const unsigned short* bS = B + (size_t)(n0 + srow) * ldb + scol;

  auto stA = [&](int buf, int h, int tt) {
    int ttc = tt < nt ? tt : nt - 1;
    const unsigned short* s0 = aS + (size_t)(h << 7) * lda + (ttc << 6);
#pragma unroll
    for (int c = 0; c < 2; ++c)
      __builtin_amdgcn_global_load_lds(
          (const __attribute__((address_space(1))) void*)(s0 + (size_t)(c << 6) * lda),
          (__attribute__((address_space(3))) void*)((char*)&lA[buf][h][0] + (c << 13) + (tid << 4)),
          16, 0, 0);
  };
  auto stB = [&](int buf, int h, int tt) {
    int ttc = tt < nt ? tt : nt - 1;
    const unsigned short* s0 = bS + (size_t)(h << 7) * ldb + (ttc << 6);
#pragma unroll
    for (int c = 0; c < 2; ++c)
      __builtin_amdgcn_global_load_lds(
          (const __attribute__((address_space(1))) void*)(s0 + (size_t)(c << 6) * ldb),
          (__attribute__((address_space(3))) void*)((char*)&lB[buf][h][0] + (c << 13) + (tid << 4)),
          16, 0, 0);
  };

  f32x4 acc[8][4];
#pragma unroll
  for (int i = 0; i < 8; ++i)
#pragma unroll
    for (int j = 0; j < 4; ++j) acc[i][j] = f32x4{0.f, 0.f, 0.f, 0.f};

  KLOOP_BODY

  if (isScore) {
    unsigned short* Ch = S + (size_t)z * 2048 * 2048;
#pragma unroll
    for (int mig = 0; mig < 8; ++mig) {
      const int row = m0 + (mig >> 2) * 128 + wm * 64 + (mig & 3) * 16 + (kg << 2);
#pragma unroll
      for (int jj = 0; jj < 4; ++jj) {
        const int r = row + jj;
        float rs = 0.f;
#pragma unroll
        for (int njg = 0; njg < 4; ++njg) {
          const int col = n0 + (njg >> 1) * 128 + wn * 32 + (njg & 1) * 16 + fr;
          const float ee = (col <= r) ? __expf(acc[mig][njg][jj] * 0.03125f) : 0.f;
          rs += ee;
          Ch[(size_t)r * 2048 + col] = f2b(ee);
        }
#pragma unroll
        for (int mk = 1; mk <= 8; mk <<= 1) rs += __shfl_xor(rs, mk, 64);
        if (fr == 0) atomicAdd(&rows[z * 2048 + r], rs);
      }
    }
  } else {
    // Vt[row][col] = acc + bv[row]; ldc = 8192
#pragma unroll
    for (int mig = 0; mig < 8; ++mig)
#pragma unroll
      for (int njg = 0; njg < 4; ++njg) {
        const int row = m0 + (mig >> 2) * 128 + wm * 64 + (mig & 3) * 16 + (kg << 2);
        const int col = n0 + (njg >> 1) * 128 + wn * 32 + (njg & 1) * 16 + fr;
        f32x4 v = acc[mig][njg];
#pragma unroll
        for (int jj = 0; jj < 4; ++jj)
          Vt[(size_t)(row + jj) * 8192 + col] = f2b(v[jj] + bv[row + jj]);
      }
  }
}

// ---------------- gemm2ph: 256x128 2-phase (out-proj, f32 + bias[col]) -----
__global__ __launch_bounds__(512, 2)
void gemm2ph(const unsigned short* __restrict__ A, const unsigned short* __restrict__ B,
             float* __restrict__ Cout, const float* __restrict__ bias,
             int K, int lda, int ldb, int ldc)
{
  const int gx = gridDim.x;
  const int nwg = gx * gridDim.y;
  int flat = blockIdx.y * gx + blockIdx.x;
  { const int q = nwg >> 3, r = nwg & 7, xc = flat & 7, i = flat >> 3;
    flat = (xc < r ? xc * (q + 1) : r * (q + 1) + (xc - r) * q) + i; }
  const int m0 = (flat / gx) << 8;
  const int n0 = (flat % gx) << 7;
  const int nt = K >> 6;

  __shared__ unsigned short lA[2][2][8192];   // 64 KB
  __shared__ unsigned short lB[2][8192];      // 32 KB

  const int tid = threadIdx.x, lane = tid & 63, wid = tid >> 6;
  const int wm = wid >> 2, wn = wid & 3;
  const int fr = lane & 15, kg = lane >> 4;

  const int xorv = (fr & 7) << 4;
  int offA[4][2], offB[2][2];
#pragma unroll
  for (int mi = 0; mi < 4; ++mi)
#pragma unroll
    for (int ks = 0; ks < 2; ++ks)
      offA[mi][ks] = ((wm << 6) + (mi << 4) + fr) * 128 + (((ks << 6) + (kg << 4)) ^ xorv);
#pragma unroll
  for (int nj = 0; nj < 2; ++nj)
#pragma unroll
    for (int ks = 0; ks < 2; ++ks)
      offB[nj][ks] = ((wn << 5) + (nj << 4) + fr) * 128 + (((ks << 6) + (kg << 4)) ^ xorv);

  const int srow = tid >> 3;
  const int scol = (((tid & 7) ^ (srow & 7)) << 3);
  const unsigned short* aS = A + (size_t)(m0 + srow) * lda + scol;
  const unsigned short* bS = B + (size_t)(n0 + srow) * ldb + scol;

  auto stA = [&](int buf, int h, int tt) {
    int ttc = tt < nt ? tt : nt - 1;
    const unsigned short* s0 = aS + (size_t)(h << 7) * lda + (ttc << 6);
#pragma unroll
    for (int c = 0; c < 2; ++c)
      __builtin_amdgcn_global_load_lds(
          (const __attribute__((address_space(1))) void*)(s0 + (size_t)(c << 6) * lda),
          (__attribute__((address_space(3))) void*)((char*)&lA[buf][h][0] + (c << 13) + (tid << 4)),
          16, 0, 0);
  };
  auto stB = [&](int buf, int tt) {
    int ttc = tt < nt ? tt : nt - 1;
    const unsigned short* s0 = bS + (ttc << 6);
#pragma unroll
    for (int c = 0; c < 2; ++c)
      __builtin_amdgcn_global_load_lds(
          (const __attribute__((address_space(1))) void*)(s0 + (size_t)(c << 6) * ldb),
          (__attribute__((address_space(3))) void*)((char*)&lB[buf][0] + (c << 13) + (tid << 4)),
          16, 0, 0);
  };

  f32x4 acc[8][2];
#pragma unroll
  for (int i = 0; i < 8; ++i)
#pragma unroll
    for (int j = 0; j < 2; ++j) acc[i][j] = f32x4{0.f, 0.f, 0.f, 0.f};

  stB(0, 0); stA(0, 0, 0); stA(0, 1, 0);
  asm volatile("s_waitcnt vmcnt(2)" ::: "memory");
  __builtin_amdgcn_s_barrier();

  for (int t = 0; t < nt; ++t) {
    const int buf = t & 1, nbuf = buf ^ 1;
    const char* Ab0 = (const char*)&lA[buf][0][0];
    const char* Ab1 = (const char*)&lA[buf][1][0];
    const char* Bbp = (const char*)&lB[buf][0];

    short8 a0[4][2], a1[4][2], b0[2][2];

    RD_A(a0, Ab0);
    RD_B(b0, Bbp);
    stB(nbuf, t + 1); stA(nbuf, 0, t + 1);
    asm volatile("s_waitcnt vmcnt(4)" ::: "memory");
    __builtin_amdgcn_s_barrier();
    MFMA16(a0, b0, 0, 0);

    RD_A(a1, Ab1);
    stA(nbuf, 1, t + 1);
    asm volatile("s_waitcnt vmcnt(2)" ::: "memory");
    __builtin_amdgcn_s_barrier();
    MFMA16(a1, b0, 4, 0);
  }
  asm volatile("s_waitcnt vmcnt(0)" ::: "memory");

#pragma unroll
  for (int mig = 0; mig < 8; ++mig)
#pragma unroll
    for (int njg = 0; njg < 2; ++njg) {
      const int row = m0 + (mig >> 2) * 128 + wm * 64 + (mig & 3) * 16 + (kg << 2);
      const int col = n0 + wn * 32 + njg * 16 + fr;
      f32x4 v = acc[mig][njg];
      const float bb = bias[col];
#pragma unroll
      for (int jj = 0; jj < 4; ++jj)
        Cout[(size_t)(row + jj) * ldc + col] = v[jj] + bb;
    }
}

// -------- split-K4 reduce + normalize: attn = (P0+P1+P2+P3)/rowsum --------
__global__ __launch_bounds__(256)
void reduce_pv4(const unsigned short* __restrict__ p0,
                const unsigned short* __restrict__ p1,
                const unsigned short* __restrict__ p2,
                const unsigned short* __restrict__ p3,
                const float* __restrict__ rows,
                unsigned short* __restrict__ out) {
  const size_t i = ((size_t)blockIdx.x * 256 + threadIdx.x) << 3;
  const float inv = 1.f / rows[i >> 10];
  us8 a = *(const us8*)&p0[i];
  us8 b = *(const us8*)&p1[i];
  us8 c = *(const us8*)&p2[i];
  us8 d = *(const us8*)&p3[i];
  us8 o;
#pragma unroll
  for (int j = 0; j < 8; ++j)
    o[j] = f2b((b2f(a[j]) + b2f(b[j]) + b2f(c[j]) + b2f(d[j])) * inv);
  *(us8*)&out[i] = o;
}

// ---------------- host-side launch ----------------
extern "C" void kernel_launch(void* const* d_in, const int* in_sizes, int n_in,
                              void* d_out, int out_size, void* d_ws, size_t ws_size,
                              hipStream_t stream) {
  (void)in_sizes; (void)n_in; (void)out_size; (void)ws_size;
  const float* x  = (const float*)d_in[0];
  const float* Wq = (const float*)d_in[1];
  const float* bq = (const float*)d_in[2];
  const float* Wk = (const float*)d_in[3];
  const float* bk = (const float*)d_in[4];
  const float* Wv = (const float*)d_in[5];
  const float* bv = (const float*)d_in[6];
  const float* Wo = (const float*)d_in[7];
  const float* bo = (const float*)d_in[8];

  const int B = 4, T = 2048, C = 1024;
  const int M = B * T;                                   // 8192

  unsigned short* xb    = (unsigned short*)d_ws;         // M*C ; later P2
  unsigned short* Wqkvb = xb    + (size_t)M * C;         // [Wq|Wk|Wv]
  unsigned short* Wob   = Wqkvb + (size_t)3 * C * C;
  unsigned short* QK    = Wob   + (size_t)C * C;         // M*2C [Q|K]; later P0|P1
  unsigned short* Vt    = QK    + (size_t)M * 2 * C;     // [1024][8192]
  unsigned short* S     = Vt    + (size_t)M * C;         // B*T*T e-values
  float*          bws   = (float*)(S + (size_t)B * T * T);
  float*          rowsum= bws + 4096;                    // 8192 f32
  unsigned short* P0    = QK;
  unsigned short* P1    = QK + (size_t)M * C;
  unsigned short* P2    = xb;
  unsigned short* P3    = (unsigned short*)d_out;        // scratch pre-out-proj
  unsigned short* attn  = P0;

  // 1. prep
  prep_kernel<<<12305, 256, 0, stream>>>(x, Wq, Wk, Wv, Wo, bq, bk, bv, bo,
                                         xb, Wqkvb, Wob, bws, rowsum);

  // 2. QK projection (256 blocks)
  gemm8<3, false><<<dim3(2 * C / 256, M / 256, 1), 512, 0, stream>>>(
      xb, Wqkvb, QK, bws, nullptr, C, C, C, 2 * C, 0LL, 0LL, 0LL);

  // 3. fused: scores (exp+rowsum, 144 tri blocks) + Vt-proj (128 blocks)
  fused_sv<<<272, 512, 0, stream>>>(QK, xb, Wqkvb + (size_t)2 * C * C,
                                    S, Vt, rowsum, bws + 2 * C);

  // 4. PV split-K=4: partials P0..P3 (z = batch*4 + quarter)
  gemm8<5, true><<<dim3(C / 256, T / 256, 4 * B), 512, 0, stream>>>(
      S, Vt, P0, (const float*)P2, (float*)P3, T, T, M, C,
      (long long)T * T, 2048LL, (long long)T * C);

  // 5. reduce + normalize (attn -> P0 in place)
  reduce_pv4<<<4096, 256, 0, stream>>>(P0, P1, P2, P3, rowsum, attn);

  // 6. out = attn Wo^T + bo (f32, 256 blocks BN=128)
  gemm2ph<<<dim3(C / 128, M / 256, 1), 512, 0, stream>>>(
      attn, Wob, (float*)d_out, bws + 3 * C, C, C, C, C);
}

// Round 13
// 183.943 us; speedup vs baseline: 1.5981x; 1.0509x over previous
//
#include <hip/hip_runtime.h>

// Masked self-attention, B=4 T=2048 C=1024 (single head, head dim = C).
// Round-8 pipeline + (i) template-faithful 8-barrier K-loop (2nd barrier
// after each MFMA cluster, no forced lgkm drains), (ii) PV split-K2.
//  gemm8  : 256x256 / BK=64 / 8-wave pipelined, counted vmcnt(4)/K-tile.
//           EPI 3 = bf16+bias[col] (QK), 5 = split-K2 partial (PV),
//           6 = scores exp+rowsum (tri early-exit).
//  gemm2ph: 256x128 2-phase (Vt-proj bf16+bias[row]; out-proj f32+bias[col]).
// LDS swizzle: 16B-slot ^= (row&7), both-sides. T1 XCD-bijective swizzle.
// Softmax fused in scores epilogue; reduce_pv2 divides by rowsum.
// Pipeline: prep | QK | Vt | scores | PV splitK2 | reduce2 | out.

typedef __attribute__((ext_vector_type(8))) short short8;
typedef __attribute__((ext_vector_type(4))) float f32x4;
typedef __attribute__((ext_vector_type(4))) unsigned short us4;
typedef __attribute__((ext_vector_type(8))) unsigned short us8;
typedef __attribute__((ext_vector_type(4))) float fl4;

__device__ __forceinline__ unsigned short f2b(float f) {
  unsigned int u = __builtin_bit_cast(unsigned int, f);
  u += 0x7fffu + ((u >> 16) & 1u);   // round-to-nearest-even
  return (unsigned short)(u >> 16);
}
__device__ __forceinline__ float b2f(unsigned short h) {
  unsigned int u = ((unsigned int)h) << 16;
  return __builtin_bit_cast(float, u);
}

// ---------------- merged prep: converts + bias packing + rowsum zero -------
__global__ __launch_bounds__(256) void prep_kernel(
    const float* __restrict__ x,
    const float* __restrict__ Wq, const float* __restrict__ Wk,
    const float* __restrict__ Wv, const float* __restrict__ Wo,
    const float* __restrict__ bq, const float* __restrict__ bk,
    const float* __restrict__ bv, const float* __restrict__ bo,
    unsigned short* __restrict__ xb, unsigned short* __restrict__ Wqkvb,
    unsigned short* __restrict__ Wob, float* __restrict__ bws,
    float* __restrict__ rows) {
  const int bid = blockIdx.x;
  if (bid < 8192) {
    const int i = bid * 256 + threadIdx.x;
    fl4 f = *(const fl4*)&x[(size_t)i << 2];
    us4 o;
#pragma unroll
    for (int j = 0; j < 4; ++j) o[j] = f2b(f[j]);
    *(us4*)&xb[(size_t)i << 2] = o;
  } else if (bid < 12288) {
    const int w = (bid - 8192) >> 10;
    const int i = ((bid - 8192) & 1023) * 256 + threadIdx.x;
    const float* s = w == 0 ? Wq : w == 1 ? Wk : w == 2 ? Wv : Wo;
    unsigned short* d = w < 3 ? Wqkvb + (size_t)w * 1024 * 1024 : Wob;
    fl4 f = *(const fl4*)&s[(size_t)i << 2];
    us4 o;
#pragma unroll
    for (int j = 0; j < 4; ++j) o[j] = f2b(f[j]);
    *(us4*)&d[(size_t)i << 2] = o;
  } else if (bid < 12304) {
    const int i = (bid - 12288) * 256 + threadIdx.x;
    const int sel = i >> 10, idx = i & 1023;
    const float* p = sel == 0 ? bq : sel == 1 ? bk : sel == 2 ? bv : bo;
    bws[i] = p[idx];
  } else {
    for (int k = threadIdx.x; k < 8192; k += 256) rows[k] = 0.f;
  }
}

#define RD_A(dst, basep)                                                   \
  _Pragma("unroll") for (int mi = 0; mi < 4; ++mi)                         \
  _Pragma("unroll") for (int ks = 0; ks < 2; ++ks)                         \
      dst[mi][ks] = *(const short8*)((basep) + offA[mi][ks]);

#define RD_B(dst, basep)                                                   \
  _Pragma("unroll") for (int nj = 0; nj < 2; ++nj)                         \
  _Pragma("unroll") for (int ks = 0; ks < 2; ++ks)                         \
      dst[nj][ks] = *(const short8*)((basep) + offB[nj][ks]);

#define MFMA16(AF, BF, MI0, NJ0)                                           \
  __builtin_amdgcn_s_setprio(1);                                           \
  _Pragma("unroll") for (int ks = 0; ks < 2; ++ks)                         \
  _Pragma("unroll") for (int mi = 0; mi < 4; ++mi)                         \
  _Pragma("unroll") for (int nj = 0; nj < 2; ++nj)                         \
      acc[(MI0) + mi][(NJ0) + nj] = __builtin_amdgcn_mfma_f32_16x16x32_bf16( \
          AF[mi][ks], BF[nj][ks], acc[(MI0) + mi][(NJ0) + nj], 0, 0, 0);   \
  __builtin_amdgcn_s_setprio(0);

// 8-barrier pipelined K-loop (template barrier discipline: 2 barriers/phase).
#define KLOOP_BODY                                                         \
  stA(0, 0, 0); stB(0, 0, 0); stA(0, 1, 0); stB(0, 1, 0);                  \
  stB(1, 0, 1); stA(1, 1, 1);                                              \
  asm volatile("s_waitcnt vmcnt(4)" ::: "memory");                         \
  __builtin_amdgcn_s_barrier();                                            \
  for (int t = 0; t < nt; ++t) {                                           \
    const int buf = t & 1, nbuf = buf ^ 1;                                 \
    const char* Ab0 = (const char*)&lA[buf][0][0];                         \
    const char* Ab1 = (const char*)&lA[buf][1][0];                         \
    const char* Bb0 = (const char*)&lB[buf][0][0];                         \
    const char* Bb1 = (const char*)&lB[buf][1][0];                         \
    short8 a0[4][2], a1[4][2], b0[2][2], b1[2][2];                         \
    RD_A(a0, Ab0);                                                         \
    RD_B(b0, Bb0);                                                         \
    stB(nbuf, 1, t + 1);                                                   \
    __builtin_amdgcn_s_barrier();                                          \
    RD_A(a1, Ab1);                                                         \
    MFMA16(a0, b0, 0, 0);                                                  \
    __builtin_amdgcn_s_barrier();                                          \
    stA(nbuf, 0, t + 1);                                                   \
    __builtin_amdgcn_s_barrier();                                          \
    RD_B(b1, Bb1);                                                         \
    MFMA16(a1, b0, 4, 0);                                                  \
    __builtin_amdgcn_s_barrier();                                          \
    stB(buf, 0, t + 2);                                                    \
    __builtin_amdgcn_s_barrier();                                          \
    MFMA16(a1, b1, 4, 2);                                                  \
    __builtin_amdgcn_s_barrier();                                          \
    stA(buf, 1, t + 2);                                                    \
    asm volatile("s_waitcnt vmcnt(4)" ::: "memory");                       \
    __builtin_amdgcn_s_barrier();                                          \
    MFMA16(a0, b1, 0, 2);                                                  \
    __builtin_amdgcn_s_barrier();                                          \
  }                                                                        \
  asm volatile("s_waitcnt vmcnt(0)" ::: "memory");

// ---------------- gemm8: 256x256 8-barrier pipelined ----------------
// EPI: 3 = bf16 + bias[col]   5 = split-K2 bf16 partial (half -> P0|P1)
//      6 = scores: bf16 exp(v*scale) causal-masked + rowsum atomics
template<int EPI, bool SPLIT2, bool SKIP_UPPER>
__global__ __launch_bounds__(512, 2)
void gemm8(const unsigned short* __restrict__ A, const unsigned short* __restrict__ B,
           void* __restrict__ Cout, const float* __restrict__ bias,
           float* __restrict__ rows, float scale, int K,
           int lda, int ldb, int ldc,
           long long sAz, long long sBz, long long sCz)
{
  const int gx = gridDim.x;
  const int nwg = gx * gridDim.y;
  int flat = blockIdx.y * gx + blockIdx.x;
  { const int q = nwg >> 3, r = nwg & 7, xc = flat & 7, i = flat >> 3;
    flat = (xc < r ? xc * (q + 1) : r * (q + 1) + (xc - r) * q) + i; }
  const int m0 = (flat / gx) << 8;
  const int n0 = (flat % gx) << 8;
  if (SKIP_UPPER && n0 > m0 + 255) return;   // fully-masked score block
  const int zraw = blockIdx.z;
  const int z = SPLIT2 ? (zraw >> 1) : zraw;

  int kBeg = 0, kEnd = K;
  if (SPLIT2) {                        // balanced causal half (PV)
    const int kFull = m0 + 256;        // multiple of 256
    const int kMid = kFull >> 1;       // multiple of 128
    kBeg = (zraw & 1) ? kMid : 0;
    kEnd = (zraw & 1) ? kFull : kMid;
  }
  const int nt = (kEnd - kBeg) >> 6;

  __shared__ unsigned short lA[2][2][8192];
  __shared__ unsigned short lB[2][2][8192];

  const int tid = threadIdx.x, lane = tid & 63, wid = tid >> 6;
  const int wm = wid >> 2, wn = wid & 3;
  const int fr = lane & 15, kg = lane >> 4;

  const unsigned short* Ab = A + (size_t)z * sAz;
  const unsigned short* Bb = B + (size_t)z * sBz;

  const int xorv = (fr & 7) << 4;
  int offA[4][2], offB[2][2];
#pragma unroll
  for (int mi = 0; mi < 4; ++mi)
#pragma unroll
    for (int ks = 0; ks < 2; ++ks)
      offA[mi][ks] = ((wm << 6) + (mi << 4) + fr) * 128 + (((ks << 6) + (kg << 4)) ^ xorv);
#pragma unroll
  for (int nj = 0; nj < 2; ++nj)
#pragma unroll
    for (int ks = 0; ks < 2; ++ks)
      offB[nj][ks] = ((wn << 5) + (nj << 4) + fr) * 128 + (((ks << 6) + (kg << 4)) ^ xorv);

  const int srow = tid >> 3;
  const int scol = (((tid & 7) ^ (srow & 7)) << 3);
  const unsigned short* aS = Ab + (size_t)(m0 + srow) * lda + scol + kBeg;
  const unsigned short* bS = Bb + (size_t)(n0 + srow) * ldb + scol + kBeg;

  auto stA = [&](int buf, int h, int tt) {
    int ttc = tt < nt ? tt : nt - 1;
    const unsigned short* s0 = aS + (size_t)(h << 7) * lda + (ttc << 6);
#pragma unroll
    for (int c = 0; c < 2; ++c)
      __builtin_amdgcn_global_load_lds(
          (const __attribute__((address_space(1))) void*)(s0 + (size_t)(c << 6) * lda),
          (__attribute__((address_space(3))) void*)((char*)&lA[buf][h][0] + (c << 13) + (tid << 4)),
          16, 0, 0);
  };
  auto stB = [&](int buf, int h, int tt) {
    int ttc = tt < nt ? tt : nt - 1;
    const unsigned short* s0 = bS + (size_t)(h << 7) * ldb + (ttc << 6);
#pragma unroll
    for (int c = 0; c < 2; ++c)
      __builtin_amdgcn_global_load_lds(
          (const __attribute__((address_space(1))) void*)(s0 + (size_t)(c << 6) * ldb),
          (__attribute__((address_space(3))) void*)((char*)&lB[buf][h][0] + (c << 13) + (tid << 4)),
          16, 0, 0);
  };

  f32x4 acc[8][4];
#pragma unroll
  for (int i = 0; i < 8; ++i)
#pragma unroll
    for (int j = 0; j < 4; ++j) acc[i][j] = f32x4{0.f, 0.f, 0.f, 0.f};

  KLOOP_BODY

  if (EPI == 6) {
    unsigned short* Ch = (unsigned short*)Cout + (size_t)z * sCz;
#pragma unroll
    for (int mig = 0; mig < 8; ++mig) {
      const int row = m0 + (mig >> 2) * 128 + wm * 64 + (mig & 3) * 16 + (kg << 2);
#pragma unroll
      for (int jj = 0; jj < 4; ++jj) {
        const int r = row + jj;
        float rs = 0.f;
#pragma unroll
        for (int njg = 0; njg < 4; ++njg) {
          const int col = n0 + (njg >> 1) * 128 + wn * 32 + (njg & 1) * 16 + fr;
          const float ee = (col <= r) ? __expf(acc[mig][njg][jj] * scale) : 0.f;
          rs += ee;
          Ch[(size_t)r * ldc + col] = f2b(ee);
        }
#pragma unroll
        for (int mk = 1; mk <= 8; mk <<= 1) rs += __shfl_xor(rs, mk, 64);
        if (fr == 0) atomicAdd(&rows[z * 2048 + r], rs);
      }
    }
    return;
  }
#pragma unroll
  for (int mig = 0; mig < 8; ++mig)
#pragma unroll
    for (int njg = 0; njg < 4; ++njg) {
      const int row = m0 + (mig >> 2) * 128 + wm * 64 + (mig & 3) * 16 + (kg << 2);
      const int col = n0 + (njg >> 1) * 128 + wn * 32 + (njg & 1) * 16 + fr;
      f32x4 v = acc[mig][njg];
      if (EPI == 3) {
        unsigned short* Ch = (unsigned short*)Cout;
        const float bb = bias[col];
#pragma unroll
        for (int jj = 0; jj < 4; ++jj)
          Ch[(size_t)(row + jj) * ldc + col] = f2b(v[jj] + bb);
      } else {   // EPI == 5: split-K2 partial; half selects P0|P1
        unsigned short* Ch = (unsigned short*)Cout +
            (size_t)(zraw & 1) * 8388608 + (size_t)z * sCz;
#pragma unroll
        for (int jj = 0; jj < 4; ++jj)
          Ch[(size_t)(row + jj) * ldc + col] = f2b(v[jj]);
      }
    }
}

// ---------------- gemm2ph: 256x128 2-phase, 4-barrier ----------------
// EPI: 2 = f32 + bias[col] (out-proj)   4 = bf16 + bias[row] (Vt-proj)
template<int EPI>
__global__ __launch_bounds__(512, 2)
void gemm2ph(const unsigned short* __restrict__ A, const unsigned short* __restrict__ B,
             void* __restrict__ Cout, const float* __restrict__ bias,
             int K, int lda, int ldb, int ldc)
{
  const int gx = gridDim.x;
  const int nwg = gx * gridDim.y;
  int flat = blockIdx.y * gx + blockIdx.x;
  { const int q = nwg >> 3, r = nwg & 7, xc = flat & 7, i = flat >> 3;
    flat = (xc < r ? xc * (q + 1) : r * (q + 1) + (xc - r) * q) + i; }
  const int m0 = (flat / gx) << 8;
  const int n0 = (flat % gx) << 7;
  const int nt = K >> 6;

  __shared__ unsigned short lA[2][2][8192];   // 64 KB
  __shared__ unsigned short lB[2][8192];      // 32 KB

  const int tid = threadIdx.x, lane = tid & 63, wid = tid >> 6;
  const int wm = wid >> 2, wn = wid & 3;
  const int fr = lane & 15, kg = lane >> 4;

  const int xorv = (fr & 7) << 4;
  int offA[4][2], offB[2][2];
#pragma unroll
  for (int mi = 0; mi < 4; ++mi)
#pragma unroll
    for (int ks = 0; ks < 2; ++ks)
      offA[mi][ks] = ((wm << 6) + (mi << 4) + fr) * 128 + (((ks << 6) + (kg << 4)) ^ xorv);
#pragma unroll
  for (int nj = 0; nj < 2; ++nj)
#pragma unroll
    for (int ks = 0; ks < 2; ++ks)
      offB[nj][ks] = ((wn << 5) + (nj << 4) + fr) * 128 + (((ks << 6) + (kg << 4)) ^ xorv);

  const int srow = tid >> 3;
  const int scol = (((tid & 7) ^ (srow & 7)) << 3);
  const unsigned short* aS = A + (size_t)(m0 + srow) * lda + scol;
  const unsigned short* bS = B + (size_t)(n0 + srow) * ldb + scol;

  auto stA = [&](int buf, int h, int tt) {
    int ttc = tt < nt ? tt : nt - 1;
    const unsigned short* s0 = aS + (size_t)(h << 7) * lda + (ttc << 6);
#pragma unroll
    for (int c = 0; c < 2; ++c)
      __builtin_amdgcn_global_load_lds(
          (const __attribute__((address_space(1))) void*)(s0 + (size_t)(c << 6) * lda),
          (__attribute__((address_space(3))) void*)((char*)&lA[buf][h][0] + (c << 13) + (tid << 4)),
          16, 0, 0);
  };
  auto stB = [&](int buf, int tt) {
    int ttc = tt < nt ? tt : nt - 1;
    const unsigned short* s0 = bS + (ttc << 6);
#pragma unroll
    for (int c = 0; c < 2; ++c)
      __builtin_amdgcn_global_load_lds(
          (const __attribute__((address_space(1))) void*)(s0 + (size_t)(c << 6) * ldb),
          (__attribute__((address_space(3))) void*)((char*)&lB[buf][0] + (c << 13) + (tid << 4)),
          16, 0, 0);
  };

  f32x4 acc[8][2];
#pragma unroll
  for (int i = 0; i < 8; ++i)
#pragma unroll
    for (int j = 0; j < 2; ++j) acc[i][j] = f32x4{0.f, 0.f, 0.f, 0.f};

  stB(0, 0); stA(0, 0, 0); stA(0, 1, 0);
  asm volatile("s_waitcnt vmcnt(2)" ::: "memory");
  __builtin_amdgcn_s_barrier();

  for (int t = 0; t < nt; ++t) {
    const int buf = t & 1, nbuf = buf ^ 1;
    const char* Ab0 = (const char*)&lA[buf][0][0];
    const char* Ab1 = (const char*)&lA[buf][1][0];
    const char* Bbp = (const char*)&lB[buf][0];

    short8 a0[4][2], a1[4][2], b0[2][2];

    RD_A(a0, Ab0);
    RD_B(b0, Bbp);
    stB(nbuf, t + 1); stA(nbuf, 0, t + 1);
    asm volatile("s_waitcnt vmcnt(4)" ::: "memory");
    __builtin_amdgcn_s_barrier();
    MFMA16(a0, b0, 0, 0);
    __builtin_amdgcn_s_barrier();

    RD_A(a1, Ab1);
    stA(nbuf, 1, t + 1);
    asm volatile("s_waitcnt vmcnt(2)" ::: "memory");
    __builtin_amdgcn_s_barrier();
    MFMA16(a1, b0, 4, 0);
    __builtin_amdgcn_s_barrier();
  }
  asm volatile("s_waitcnt vmcnt(0)" ::: "memory");

#pragma unroll
  for (int mig = 0; mig < 8; ++mig)
#pragma unroll
    for (int njg = 0; njg < 2; ++njg) {
      const int row = m0 + (mig >> 2) * 128 + wm * 64 + (mig & 3) * 16 + (kg << 2);
      const int col = n0 + wn * 32 + njg * 16 + fr;
      f32x4 v = acc[mig][njg];
      if (EPI == 2) {
        float* Cf = (float*)Cout;
        const float bb = bias[col];
#pragma unroll
        for (int jj = 0; jj < 4; ++jj)
          Cf[(size_t)(row + jj) * ldc + col] = v[jj] + bb;
      } else {   // EPI == 4: bias by row (Vt-proj)
        unsigned short* Ch = (unsigned short*)Cout;
#pragma unroll
        for (int jj = 0; jj < 4; ++jj)
          Ch[(size_t)(row + jj) * ldc + col] = f2b(v[jj] + bias[row + jj]);
      }
    }
}

// -------- split-K2 reduce + normalize: attn = (P0+P1)/rowsum --------
__global__ __launch_bounds__(256)
void reduce_pv2(const unsigned short* __restrict__ p0,
                const unsigned short* __restrict__ p1,
                const float* __restrict__ rows,
                unsigned short* __restrict__ out) {
  const size_t i = ((size_t)blockIdx.x * 256 + threadIdx.x) << 3;
  const float inv = 1.f / rows[i >> 10];
  us8 a = *(const us8*)&p0[i];
  us8 b = *(const us8*)&p1[i];
  us8 o;
#pragma unroll
  for (int j = 0; j < 8; ++j)
    o[j] = f2b((b2f(a[j]) + b2f(b[j])) * inv);
  *(us8*)&out[i] = o;
}

// ---------------- host-side launch ----------------
extern "C" void kernel_launch(void* const* d_in, const int* in_sizes, int n_in,
                              void* d_out, int out_size, void* d_ws, size_t ws_size,
                              hipStream_t stream) {
  (void)in_sizes; (void)n_in; (void)out_size; (void)ws_size;
  const float* x  = (const float*)d_in[0];
  const float* Wq = (const float*)d_in[1];
  const float* bq = (const float*)d_in[2];
  const float* Wk = (const float*)d_in[3];
  const float* bk = (const float*)d_in[4];
  const float* Wv = (const float*)d_in[5];
  const float* bv = (const float*)d_in[6];
  const float* Wo = (const float*)d_in[7];
  const float* bo = (const float*)d_in[8];

  const int B = 4, T = 2048, C = 1024;
  const int M = B * T;                                   // 8192

  unsigned short* xb    = (unsigned short*)d_ws;         // M*C
  unsigned short* Wqkvb = xb    + (size_t)M * C;         // [Wq|Wk|Wv]
  unsigned short* Wob   = Wqkvb + (size_t)3 * C * C;
  unsigned short* QK    = Wob   + (size_t)C * C;         // M*2C [Q|K]; later P0|P1
  unsigned short* Vt    = QK    + (size_t)M * 2 * C;     // [1024][8192]
  unsigned short* S     = Vt    + (size_t)M * C;         // B*T*T e-values
  float*          bws   = (float*)(S + (size_t)B * T * T);
  float*          rowsum= bws + 4096;                    // 8192 f32
  unsigned short* P0    = QK;
  unsigned short* P1    = QK + (size_t)M * C;
  unsigned short* attn  = P0;

  // 1. prep
  prep_kernel<<<12305, 256, 0, stream>>>(x, Wq, Wk, Wv, Wo, bq, bk, bv, bo,
                                         xb, Wqkvb, Wob, bws, rowsum);

  // 2. QK projection (256 blocks)
  gemm8<3, false, false><<<dim3(2 * C / 256, M / 256, 1), 512, 0, stream>>>(
      xb, Wqkvb, QK, bws, nullptr, 1.f, C, C, C, 2 * C, 0LL, 0LL, 0LL);

  // 3. Vt = Wv @ x^T + bv[row] (256 blocks, BN=128)
  gemm2ph<4><<<dim3(M / 128, C / 256, 1), 512, 0, stream>>>(
      Wqkvb + (size_t)2 * C * C, xb, Vt, bws + 2 * C, C, C, C, M);

  // 4. scores: S = exp(Q K^T / 32) causal-masked + rowsum atomics
  gemm8<6, false, true><<<dim3(T / 256, T / 256, B), 512, 0, stream>>>(
      QK, QK + C, S, nullptr, rowsum, 0.03125f, C, 2 * C, 2 * C, T,
      (long long)T * 2 * C, (long long)T * 2 * C, (long long)T * T);

  // 5. PV split-K2: partials P0|P1 (z = batch*2 + half), 256 blocks
  gemm8<5, true, false><<<dim3(C / 256, T / 256, 2 * B), 512, 0, stream>>>(
      S, Vt, P0, nullptr, nullptr, 1.f, T, T, M, C,
      (long long)T * T, 2048LL, (long long)T * C);

  // 6. reduce + normalize (attn -> P0 in place)
  reduce_pv2<<<4096, 256, 0, stream>>>(P0, P1, rowsum, attn);

  // 7. out = attn Wo^T + bo (f32, 256 blocks BN=128)
  gemm2ph<2><<<dim3(C / 128, M / 256, 1), 512, 0, stream>>>(
      attn, Wob, d_out, bws + 3 * C, C, C, C, C);
}